// Round 7
// baseline (396.008 us; speedup 1.0000x reference)
//
#include <hip/hip_runtime.h>
#include <hip/hip_bf16.h>

// GCN 2-layer forward on MI355X — CSR via two-level LDS counting sort
// (zero global atomics). Round-7: gemm1 = one WAVE per row, fully-coalesced
// 1KiB wave-loads of x (round 6 was 1.5x over-fetching: per-lane 2KB-strided
// walks thrashed L1), W1 fragment in VGPRs (128/lane), in-wave butterfly
// reduce, dinv folded at the store (part/combine pass deleted).
// Inputs: x[N,512] f32, edge_index[2,E] int32, edge_weight[E] f32,
//         W1[512,16], b1[16], W2[16,10], b2[10]
// Outputs (concat): log_softmax(logits)[N,10], x1[N,16]

#define NF1 16   // hidden
#define NF2 10   // classes
#define FIN 512
#define EPB 8192 // edges per coarse block (256 thr * 32)

typedef unsigned long long ull;

// ---------- A: coarse count (col>>9) into per-block histograms ----------
__global__ __launch_bounds__(256) void coarse_count_kernel(const int* __restrict__ col,
                                                           int* __restrict__ blkhist,
                                                           int E, int NB, int NBLK) {
    __shared__ int lh[256];
    int t = threadIdx.x;
    lh[t] = 0;
    __syncthreads();
    int base = blockIdx.x * EPB;
    int cnt = min(EPB, E - base);
    for (int i = t; i < cnt; i += 256)
        atomicAdd(&lh[col[base + i] >> 9], 1);
    __syncthreads();
    if (t < NB) blkhist[t * NBLK + blockIdx.x] = lh[t];
}

// ---------- B1: per-bucket exclusive scan over blocks (parallel) ----------
__global__ __launch_bounds__(512) void bucket_scan_kernel(int* __restrict__ blkhist,
                                                          int* __restrict__ btot,
                                                          int NBLK) {
    __shared__ int s[512];
    int t = threadIdx.x;
    int* p = blkhist + (size_t)blockIdx.x * NBLK;
    int carry = 0;
    for (int base = 0; base < NBLK; base += 512) {
        int idx = base + t;
        int v = (idx < NBLK) ? p[idx] : 0;
        s[t] = v;
        __syncthreads();
        for (int off = 1; off < 512; off <<= 1) {
            int u = (t >= off) ? s[t - off] : 0;
            __syncthreads();
            s[t] += u;
            __syncthreads();
        }
        if (idx < NBLK) p[idx] = s[t] - v + carry;
        carry += s[511];
        __syncthreads();
    }
    if (t == 0) btot[blockIdx.x] = carry;
}

// ---------- B2: scan bucket totals -> bbase ----------
__global__ __launch_bounds__(256) void base_scan_kernel(const int* __restrict__ btot,
                                                        int* __restrict__ bbase,
                                                        int* __restrict__ rowptr,
                                                        int NB, int E, int N) {
    __shared__ int s[256];
    int t = threadIdx.x;
    int v = (t < NB) ? btot[t] : 0;
    s[t] = v;
    __syncthreads();
    for (int off = 1; off < 256; off <<= 1) {
        int u = (t >= off) ? s[t - off] : 0;
        __syncthreads();
        s[t] += u;
        __syncthreads();
    }
    if (t < NB) bbase[t] = s[t] - v;
    if (t == 0) { bbase[NB] = E; rowptr[N] = E; }
}

// ---------- C: coarse scatter into bucket-ordered pool ----------
// pool entry: hi32 = (c9<<20)|row, lo32 = weight bits
__global__ __launch_bounds__(256) void coarse_scatter_kernel(const int* __restrict__ row,
                                                             const int* __restrict__ col,
                                                             const float* __restrict__ ew,
                                                             const int* __restrict__ blkhist,
                                                             const int* __restrict__ bbase,
                                                             ull* __restrict__ pool,
                                                             int E, int NB, int NBLK) {
    __shared__ int cur[256];
    int t = threadIdx.x;
    if (t < NB) cur[t] = blkhist[t * NBLK + blockIdx.x] + bbase[t];
    __syncthreads();
    int base = blockIdx.x * EPB;
    int cnt = min(EPB, E - base);
    for (int i = t; i < cnt; i += 256) {
        int e = base + i;
        int c = col[e], r = row[e];
        float w = ew[e];
        int b = c >> 9, c9 = c & 511;
        int pos = atomicAdd(&cur[b], 1);
        pool[pos] = ((ull)((((unsigned)c9) << 20) | (unsigned)r) << 32) | (ull)__float_as_uint(w);
    }
}

// ---------- D: fine sort within bucket (512 cols) -> CSR (raw w), rowptr, dinv ----------
__global__ __launch_bounds__(1024) void fine_sort_kernel(const ull* __restrict__ pool,
                                                         const int* __restrict__ bbase,
                                                         ull* __restrict__ csr,
                                                         int* __restrict__ rowptr,
                                                         float* __restrict__ dinv, int N) {
    __shared__ int hist[512];
    __shared__ float wsum[512];
    __shared__ int cur[512];
    int t = threadIdx.x;
    int b = blockIdx.x;
    int bb = bbase[b], be = bbase[b + 1];
    int Ki = be - bb;
    if (t < 512) { hist[t] = 0; wsum[t] = 0.0f; }
    __syncthreads();
    for (int i = t; i < Ki; i += 1024) {
        ull p = pool[bb + i];
        unsigned hi = (unsigned)(p >> 32);
        int c9 = (hi >> 20) & 511;
        atomicAdd(&hist[c9], 1);
        atomicAdd(&wsum[c9], __uint_as_float((unsigned)p));
    }
    __syncthreads();
    int own = (t < 512) ? hist[t] : 0;
    if (t < 512) cur[t] = own;
    __syncthreads();
    for (int off = 1; off < 512; off <<= 1) {
        int v = (t >= off && t < 512) ? cur[t - off] : 0;
        __syncthreads();
        if (t < 512) cur[t] += v;
        __syncthreads();
    }
    int excl = (t < 512) ? (cur[t] - own) : 0;
    if (t < 512) cur[t] = excl;
    int c = (b << 9) + t;
    if (t < 512 && c < N) {
        rowptr[c] = bb + excl;
        dinv[c] = rsqrtf(1.0f + wsum[t]);       // deg = self(1) + sum(w)
    }
    __syncthreads();
    for (int i = t; i < Ki; i += 1024) {
        ull p = pool[bb + i];
        unsigned hi = (unsigned)(p >> 32);
        int c9 = (hi >> 20) & 511;
        unsigned r = hi & 0xFFFFFu;
        int k = atomicAdd(&cur[c9], 1);
        csr[bb + k] = ((p & 0xFFFFFFFFull) << 32) | (ull)r;   // raw weight
    }
}

// ---------- GEMM1: hs = dinv .* (x @ W1)   one wave per row ----------
// Lane l owns k in {4l..4l+3} u {256+4l..256+4l+3}; W1 fragment (8 rows x 16)
// lives in VGPRs, loaded once. x wave-loads are exactly 1 KiB contiguous.
// Butterfly (vector-halving) reduce: lane<16 ends with f = bitrev4(lane).
__global__ __launch_bounds__(256) void gemm1_kernel(const float* __restrict__ x,
                                                    const float* __restrict__ W1,
                                                    const float* __restrict__ dinv,
                                                    float* __restrict__ hs,
                                                    int N, int totalWaves) {
    int wave = (blockIdx.x * 256 + threadIdx.x) >> 6;
    int lane = threadIdx.x & 63;

    // W1 fragment: rows 4l..4l+3 (chunk a) and 256+4l..+3 (chunk b)
    float4 w[8][4];
#pragma unroll
    for (int r = 0; r < 4; r++) {
#pragma unroll
        for (int q = 0; q < 4; q++) {
            w[r][q]     = *reinterpret_cast<const float4*>(&W1[(4 * lane + r) * NF1 + 4 * q]);
            w[4 + r][q] = *reinterpret_cast<const float4*>(&W1[(256 + 4 * lane + r) * NF1 + 4 * q]);
        }
    }

    int row = wave;
    if (row >= N) return;
    float4 xa = *reinterpret_cast<const float4*>(&x[(size_t)row * FIN + 4 * lane]);
    float4 xb = *reinterpret_cast<const float4*>(&x[(size_t)row * FIN + 256 + 4 * lane]);

    for (; row < N; row += totalWaves) {
        int nrow = row + totalWaves;
        float4 xa_n, xb_n;
        if (nrow < N) {   // prefetch next row (stays in flight under compute)
            xa_n = *reinterpret_cast<const float4*>(&x[(size_t)nrow * FIN + 4 * lane]);
            xb_n = *reinterpret_cast<const float4*>(&x[(size_t)nrow * FIN + 256 + 4 * lane]);
        }

        float acc[NF1];
#pragma unroll
        for (int f = 0; f < NF1; f++) acc[f] = 0.0f;

#pragma unroll
        for (int kk = 0; kk < 4; kk++) {
            float av = (&xa.x)[kk];
            float bv = (&xb.x)[kk];
#pragma unroll
            for (int q = 0; q < 4; q++) {
                float4 wa = w[kk][q];
                float4 wb = w[4 + kk][q];
                acc[4 * q + 0] = fmaf(av, wa.x, acc[4 * q + 0]);
                acc[4 * q + 1] = fmaf(av, wa.y, acc[4 * q + 1]);
                acc[4 * q + 2] = fmaf(av, wa.z, acc[4 * q + 2]);
                acc[4 * q + 3] = fmaf(av, wa.w, acc[4 * q + 3]);
                acc[4 * q + 0] = fmaf(bv, wb.x, acc[4 * q + 0]);
                acc[4 * q + 1] = fmaf(bv, wb.y, acc[4 * q + 1]);
                acc[4 * q + 2] = fmaf(bv, wb.z, acc[4 * q + 2]);
                acc[4 * q + 3] = fmaf(bv, wb.w, acc[4 * q + 3]);
            }
        }

        // vector-halving butterfly: levels m=1,2,4,8 (vector 16->1), then 16,32
        {
            bool up = (lane & 1);
            float t[8];
#pragma unroll
            for (int j = 0; j < 8; j++) t[j] = up ? acc[j] : acc[8 + j];
#pragma unroll
            for (int j = 0; j < 8; j++) t[j] = __shfl_xor(t[j], 1);
#pragma unroll
            for (int j = 0; j < 8; j++) acc[j] = (up ? acc[8 + j] : acc[j]) + t[j];
        }
        {
            bool up = (lane & 2);
            float t[4];
#pragma unroll
            for (int j = 0; j < 4; j++) t[j] = up ? acc[j] : acc[4 + j];
#pragma unroll
            for (int j = 0; j < 4; j++) t[j] = __shfl_xor(t[j], 2);
#pragma unroll
            for (int j = 0; j < 4; j++) acc[j] = (up ? acc[4 + j] : acc[j]) + t[j];
        }
        {
            bool up = (lane & 4);
            float t[2];
#pragma unroll
            for (int j = 0; j < 2; j++) t[j] = up ? acc[j] : acc[2 + j];
#pragma unroll
            for (int j = 0; j < 2; j++) t[j] = __shfl_xor(t[j], 4);
#pragma unroll
            for (int j = 0; j < 2; j++) acc[j] = (up ? acc[2 + j] : acc[j]) + t[j];
        }
        {
            bool up = (lane & 8);
            float t0 = up ? acc[0] : acc[1];
            t0 = __shfl_xor(t0, 8);
            acc[0] = (up ? acc[1] : acc[0]) + t0;
        }
        acc[0] += __shfl_xor(acc[0], 16);
        acc[0] += __shfl_xor(acc[0], 32);

        if (lane < 16) {
            int f = ((lane & 1) << 3) | ((lane & 2) << 1) | ((lane & 4) >> 1) | ((lane & 8) >> 3);
            hs[(size_t)row * NF1 + f] = dinv[row] * acc[0];
        }
        xa = xa_n;
        xb = xb_n;
    }
}

// ---------- gather layer 1: x1[c] = b1 + di*( sum ew_i*h'[r_i] + h'[c] ) ----------
__global__ __launch_bounds__(256) void gather1_kernel(const ull* __restrict__ csr,
                                                      const int* __restrict__ rowptr,
                                                      const float* __restrict__ dinv,
                                                      const float* __restrict__ hs,
                                                      const float* __restrict__ b1,
                                                      float* __restrict__ x1, int N) {
    int t = blockIdx.x * 256 + threadIdx.x;
    int node = t >> 4, f = t & 15;
    if (node >= N) return;
    int s = rowptr[node], e = rowptr[node + 1];
    float di = dinv[node];
    float acc = hs[(size_t)node * NF1 + f];       // self-loop: h'[c]
    int i = s;
    for (; i + 1 < e; i += 2) {
        ull v0 = csr[i], v1 = csr[i + 1];
        int r0 = (int)(v0 & 0xffffffffull); float w0 = __uint_as_float((unsigned)(v0 >> 32));
        int r1 = (int)(v1 & 0xffffffffull); float w1 = __uint_as_float((unsigned)(v1 >> 32));
        acc += w0 * hs[(size_t)r0 * NF1 + f];
        acc += w1 * hs[(size_t)r1 * NF1 + f];
    }
    if (i < e) {
        ull v = csr[i];
        int r = (int)(v & 0xffffffffull); float w = __uint_as_float((unsigned)(v >> 32));
        acc += w * hs[(size_t)r * NF1 + f];
    }
    x1[(size_t)node * NF1 + f] = b1[f] + di * acc;
}

// ---------- GEMM2: hh' = dinv[j] * (relu(x1[j]) @ W2) ----------
__global__ __launch_bounds__(256) void gemm2_kernel(const float* __restrict__ x1,
                                                    const float* __restrict__ W2,
                                                    const float* __restrict__ dinv,
                                                    float* __restrict__ hh, int N) {
    int j = blockIdx.x * 256 + threadIdx.x;
    if (j >= N) return;
    float xr[NF1];
#pragma unroll
    for (int f = 0; f < NF1; f++) xr[f] = fmaxf(x1[(size_t)j * NF1 + f], 0.0f);
    float d = dinv[j];
#pragma unroll
    for (int c = 0; c < NF2; c++) {
        float acc = 0.0f;
#pragma unroll
        for (int f = 0; f < NF1; f++) acc += xr[f] * W2[f * NF2 + c];
        hh[(size_t)j * NF2 + c] = d * acc;
    }
}

// ---------- gather layer 2 + fused log-softmax ----------
__global__ __launch_bounds__(256) void gather2_lsm_kernel(const ull* __restrict__ csr,
                                                          const int* __restrict__ rowptr,
                                                          const float* __restrict__ dinv,
                                                          const float* __restrict__ hh,
                                                          const float* __restrict__ b2,
                                                          float* __restrict__ out, int N) {
    int t = blockIdx.x * 256 + threadIdx.x;
    int node = t >> 4, f = t & 15;
    bool act = (node < N) && (f < NF2);
    float acc = 0.0f;
    if (node < N) {
        int s = rowptr[node], e = rowptr[node + 1];
        float di = dinv[node];
        acc = act ? hh[(size_t)node * NF2 + f] : 0.0f;   // self-loop: hh'[c]
        int i = s;
        for (; i + 1 < e; i += 2) {
            ull v0 = csr[i], v1 = csr[i + 1];
            int r0 = (int)(v0 & 0xffffffffull); float w0 = __uint_as_float((unsigned)(v0 >> 32));
            int r1 = (int)(v1 & 0xffffffffull); float w1 = __uint_as_float((unsigned)(v1 >> 32));
            float h0 = (f < NF2) ? hh[(size_t)r0 * NF2 + f] : 0.0f;
            float h1 = (f < NF2) ? hh[(size_t)r1 * NF2 + f] : 0.0f;
            acc += w0 * h0 + w1 * h1;
        }
        if (i < e) {
            ull v = csr[i];
            int r = (int)(v & 0xffffffffull); float w = __uint_as_float((unsigned)(v >> 32));
            float hv = (f < NF2) ? hh[(size_t)r * NF2 + f] : 0.0f;
            acc += w * hv;
        }
        acc = b2[f] + di * acc;
    }
    // log-softmax across the 16-lane group (10 active lanes)
    float m = act ? acc : -INFINITY;
#pragma unroll
    for (int off = 1; off < 16; off <<= 1) m = fmaxf(m, __shfl_xor(m, off, 16));
    float p = act ? expf(acc - m) : 0.0f;
    float ssum = p;
#pragma unroll
    for (int off = 1; off < 16; off <<= 1) ssum += __shfl_xor(ssum, off, 16);
    if (act) out[(size_t)node * NF2 + f] = acc - m - logf(ssum);
}

extern "C" void kernel_launch(void* const* d_in, const int* in_sizes, int n_in,
                              void* d_out, int out_size, void* d_ws, size_t ws_size,
                              hipStream_t stream) {
    const float* x  = (const float*)d_in[0];
    const int*   ei = (const int*)d_in[1];
    const float* ew = (const float*)d_in[2];
    const float* W1 = (const float*)d_in[3];
    const float* b1 = (const float*)d_in[4];
    const float* W2 = (const float*)d_in[5];
    const float* b2 = (const float*)d_in[6];

    const int E = in_sizes[2];           // 3,200,000
    const int N = in_sizes[0] / FIN;     // 100,000
    const int* row = ei;
    const int* col = ei + E;

    const int NB   = (N + 511) >> 9;     // coarse buckets (196)
    const int NBLK = (E + EPB - 1) / EPB;

    float* out    = (float*)d_out;
    float* logits = out;                        // [N,10]
    float* x1     = out + (size_t)N * NF2;      // [N,16]

    char* ws = (char*)d_ws;
    size_t off = 0;
    auto alloc = [&](size_t bytes) { void* p = ws + off; off += (bytes + 255) / 256 * 256; return p; };
    ull*   pool    = (ull*)  alloc((size_t)E * 8);
    ull*   csr     = (ull*)  alloc((size_t)E * 8);
    float* hs      = (float*)alloc((size_t)N * NF1 * 4);       // h' = dinv*(x@W1)
    float* hh      = (float*)alloc((size_t)N * NF2 * 4 + 64);  // hh' = dinv*relu(x1)@W2
    float* dinv    = (float*)alloc((size_t)N * 4);
    int*   rowptr  = (int*)  alloc((size_t)(N + 1) * 4);
    int*   blkhist = (int*)  alloc((size_t)NB * NBLK * 4);
    int*   btot    = (int*)  alloc((size_t)NB * 4);
    int*   bbase   = (int*)  alloc((size_t)(NB + 1) * 4);
    (void)ws_size; (void)n_in; (void)out_size;

    dim3 blk(256);
    int gN  = (N + 255) / 256;
    int g16 = (N + 15) / 16;

    // build CSR (no global atomics)
    coarse_count_kernel<<<NBLK, blk, 0, stream>>>(col, blkhist, E, NB, NBLK);
    bucket_scan_kernel<<<NB, dim3(512), 0, stream>>>(blkhist, btot, NBLK);
    base_scan_kernel<<<1, blk, 0, stream>>>(btot, bbase, rowptr, NB, E, N);
    coarse_scatter_kernel<<<NBLK, blk, 0, stream>>>(row, col, ew, blkhist, bbase, pool, E, NB, NBLK);
    fine_sort_kernel<<<NB, dim3(1024), 0, stream>>>(pool, bbase, csr, rowptr, dinv, N);

    // layer 1: wave-per-row GEMM (768 blocks = 3072 waves, VGPR-limited residency)
    const int gemmBlocks = 768;
    const int totalWaves = gemmBlocks * 4;
    gemm1_kernel<<<gemmBlocks, blk, 0, stream>>>(x, W1, dinv, hs, N, totalWaves);
    gather1_kernel<<<g16, blk, 0, stream>>>(csr, rowptr, dinv, hs, b1, x1, N);

    // layer 2
    gemm2_kernel<<<gN, blk, 0, stream>>>(x1, W2, dinv, hh, N);
    gather2_lsm_kernel<<<g16, blk, 0, stream>>>(csr, rowptr, dinv, hh, b2, logits, N);
}

// Round 8
// 305.189 us; speedup vs baseline: 1.2976x; 1.2976x over previous
//
#include <hip/hip_runtime.h>
#include <hip/hip_bf16.h>

// GCN 2-layer forward on MI355X — CSR via two-level LDS counting sort
// (zero global atomics). Round-8: revert to round-6 gemm1 structure
// (no-LDS register GEMM, W1 via s_load, split-K=2 — round 7's "VGPR fragment"
// was silently demoted to LDS scratch: 25M bank conflicts, 168us) and fix the
// measured 1.5x over-fetch: each lane now loads 64 B (4 consecutive float4)
// per iteration so every cache line is fully consumed on first touch.
// Inputs: x[N,512] f32, edge_index[2,E] int32, edge_weight[E] f32,
//         W1[512,16], b1[16], W2[16,10], b2[10]
// Outputs (concat): log_softmax(logits)[N,10], x1[N,16]

#define NF1 16   // hidden
#define NF2 10   // classes
#define FIN 512
#define EPB 8192 // edges per coarse block (256 thr * 32)

typedef unsigned long long ull;

// ---------- A: coarse count (col>>9) into per-block histograms ----------
__global__ __launch_bounds__(256) void coarse_count_kernel(const int* __restrict__ col,
                                                           int* __restrict__ blkhist,
                                                           int E, int NB, int NBLK) {
    __shared__ int lh[256];
    int t = threadIdx.x;
    lh[t] = 0;
    __syncthreads();
    int base = blockIdx.x * EPB;
    int cnt = min(EPB, E - base);
    for (int i = t; i < cnt; i += 256)
        atomicAdd(&lh[col[base + i] >> 9], 1);
    __syncthreads();
    if (t < NB) blkhist[t * NBLK + blockIdx.x] = lh[t];
}

// ---------- B1: per-bucket exclusive scan over blocks (parallel) ----------
__global__ __launch_bounds__(512) void bucket_scan_kernel(int* __restrict__ blkhist,
                                                          int* __restrict__ btot,
                                                          int NBLK) {
    __shared__ int s[512];
    int t = threadIdx.x;
    int* p = blkhist + (size_t)blockIdx.x * NBLK;
    int carry = 0;
    for (int base = 0; base < NBLK; base += 512) {
        int idx = base + t;
        int v = (idx < NBLK) ? p[idx] : 0;
        s[t] = v;
        __syncthreads();
        for (int off = 1; off < 512; off <<= 1) {
            int u = (t >= off) ? s[t - off] : 0;
            __syncthreads();
            s[t] += u;
            __syncthreads();
        }
        if (idx < NBLK) p[idx] = s[t] - v + carry;
        carry += s[511];
        __syncthreads();
    }
    if (t == 0) btot[blockIdx.x] = carry;
}

// ---------- B2: scan bucket totals -> bbase ----------
__global__ __launch_bounds__(256) void base_scan_kernel(const int* __restrict__ btot,
                                                        int* __restrict__ bbase,
                                                        int* __restrict__ rowptr,
                                                        int NB, int E, int N) {
    __shared__ int s[256];
    int t = threadIdx.x;
    int v = (t < NB) ? btot[t] : 0;
    s[t] = v;
    __syncthreads();
    for (int off = 1; off < 256; off <<= 1) {
        int u = (t >= off) ? s[t - off] : 0;
        __syncthreads();
        s[t] += u;
        __syncthreads();
    }
    if (t < NB) bbase[t] = s[t] - v;
    if (t == 0) { bbase[NB] = E; rowptr[N] = E; }
}

// ---------- C: coarse scatter into bucket-ordered pool ----------
// pool entry: hi32 = (c9<<20)|row, lo32 = weight bits
__global__ __launch_bounds__(256) void coarse_scatter_kernel(const int* __restrict__ row,
                                                             const int* __restrict__ col,
                                                             const float* __restrict__ ew,
                                                             const int* __restrict__ blkhist,
                                                             const int* __restrict__ bbase,
                                                             ull* __restrict__ pool,
                                                             int E, int NB, int NBLK) {
    __shared__ int cur[256];
    int t = threadIdx.x;
    if (t < NB) cur[t] = blkhist[t * NBLK + blockIdx.x] + bbase[t];
    __syncthreads();
    int base = blockIdx.x * EPB;
    int cnt = min(EPB, E - base);
    for (int i = t; i < cnt; i += 256) {
        int e = base + i;
        int c = col[e], r = row[e];
        float w = ew[e];
        int b = c >> 9, c9 = c & 511;
        int pos = atomicAdd(&cur[b], 1);
        pool[pos] = ((ull)((((unsigned)c9) << 20) | (unsigned)r) << 32) | (ull)__float_as_uint(w);
    }
}

// ---------- D: fine sort within bucket (512 cols) -> CSR (raw w), rowptr, dinv ----------
__global__ __launch_bounds__(1024) void fine_sort_kernel(const ull* __restrict__ pool,
                                                         const int* __restrict__ bbase,
                                                         ull* __restrict__ csr,
                                                         int* __restrict__ rowptr,
                                                         float* __restrict__ dinv, int N) {
    __shared__ int hist[512];
    __shared__ float wsum[512];
    __shared__ int cur[512];
    int t = threadIdx.x;
    int b = blockIdx.x;
    int bb = bbase[b], be = bbase[b + 1];
    int Ki = be - bb;
    if (t < 512) { hist[t] = 0; wsum[t] = 0.0f; }
    __syncthreads();
    for (int i = t; i < Ki; i += 1024) {
        ull p = pool[bb + i];
        unsigned hi = (unsigned)(p >> 32);
        int c9 = (hi >> 20) & 511;
        atomicAdd(&hist[c9], 1);
        atomicAdd(&wsum[c9], __uint_as_float((unsigned)p));
    }
    __syncthreads();
    int own = (t < 512) ? hist[t] : 0;
    if (t < 512) cur[t] = own;
    __syncthreads();
    for (int off = 1; off < 512; off <<= 1) {
        int v = (t >= off && t < 512) ? cur[t - off] : 0;
        __syncthreads();
        if (t < 512) cur[t] += v;
        __syncthreads();
    }
    int excl = (t < 512) ? (cur[t] - own) : 0;
    if (t < 512) cur[t] = excl;
    int c = (b << 9) + t;
    if (t < 512 && c < N) {
        rowptr[c] = bb + excl;
        dinv[c] = rsqrtf(1.0f + wsum[t]);       // deg = self(1) + sum(w)
    }
    __syncthreads();
    for (int i = t; i < Ki; i += 1024) {
        ull p = pool[bb + i];
        unsigned hi = (unsigned)(p >> 32);
        int c9 = (hi >> 20) & 511;
        unsigned r = hi & 0xFFFFFu;
        int k = atomicAdd(&cur[c9], 1);
        csr[bb + k] = ((p & 0xFFFFFFFFull) << 32) | (ull)r;   // raw weight
    }
}

// ---------- GEMM1 (split-K=2, no LDS, full-line loads): part[half][row][f] ----------
// Each lane loads 64 B (4 consecutive float4) per iteration: every 64-B line
// is fully consumed on first touch (round 6 left 3/4 of each line to a later
// iteration and L1 thrashed -> 1.5x over-fetch). W1 via uniform s_load.
__device__ __forceinline__ void fma16(float av, const float* __restrict__ wrow,
                                      float* __restrict__ acc) {
#pragma unroll
    for (int f = 0; f < NF1; f++) acc[f] = fmaf(av, wrow[f], acc[f]);
}

__global__ __launch_bounds__(256) void gemm1_kernel(const float* __restrict__ x,
                                                    const float* __restrict__ W1,
                                                    float* __restrict__ part,
                                                    int N, int nbRow) {
    int b = blockIdx.x;
    int half = (b >= nbRow) ? 1 : 0;
    int rb = b - half * nbRow;
    int row = rb * 256 + threadIdx.x;
    if (row >= N) return;
    const int k0 = half * (FIN / 2);

    float acc[NF1];
#pragma unroll
    for (int f = 0; f < NF1; f++) acc[f] = 0.0f;

    const float* xr = x + (size_t)row * FIN + k0;
    const float* wp = W1 + (size_t)k0 * NF1;

#pragma unroll 2
    for (int k = 0; k < FIN / 2; k += 16) {
        const float4* xp = reinterpret_cast<const float4*>(xr + k);
        float4 a0 = xp[0];
        float4 a1 = xp[1];
        float4 a2 = xp[2];
        float4 a3 = xp[3];
        const float* wk = wp + (size_t)k * NF1;
        fma16(a0.x, wk + 0 * NF1, acc);
        fma16(a0.y, wk + 1 * NF1, acc);
        fma16(a0.z, wk + 2 * NF1, acc);
        fma16(a0.w, wk + 3 * NF1, acc);
        fma16(a1.x, wk + 4 * NF1, acc);
        fma16(a1.y, wk + 5 * NF1, acc);
        fma16(a1.z, wk + 6 * NF1, acc);
        fma16(a1.w, wk + 7 * NF1, acc);
        fma16(a2.x, wk + 8 * NF1, acc);
        fma16(a2.y, wk + 9 * NF1, acc);
        fma16(a2.z, wk + 10 * NF1, acc);
        fma16(a2.w, wk + 11 * NF1, acc);
        fma16(a3.x, wk + 12 * NF1, acc);
        fma16(a3.y, wk + 13 * NF1, acc);
        fma16(a3.z, wk + 14 * NF1, acc);
        fma16(a3.w, wk + 15 * NF1, acc);
    }

    float* pp = part + ((size_t)half * N + row) * NF1;
#pragma unroll
    for (int q = 0; q < 4; q++) {
        float4 o = make_float4(acc[4 * q], acc[4 * q + 1], acc[4 * q + 2], acc[4 * q + 3]);
        *reinterpret_cast<float4*>(pp + 4 * q) = o;
    }
}

// ---------- combine split-K partials and fold dinv: h' = dinv[row]*(p0+p1) ----------
__global__ __launch_bounds__(256) void combine_scale_kernel(const float* __restrict__ part,
                                                            const float* __restrict__ dinv,
                                                            float* __restrict__ hs, int N) {
    int i4 = blockIdx.x * 256 + threadIdx.x;     // float4 index
    int total = N * NF1 / 4;
    if (i4 >= total) return;
    int rowIdx = i4 >> 2;                        // 4 float4 per row
    float4 a = reinterpret_cast<const float4*>(part)[i4];
    float4 bq = reinterpret_cast<const float4*>(part + (size_t)N * NF1)[i4];
    float d = dinv[rowIdx];
    float4 o = make_float4(d * (a.x + bq.x), d * (a.y + bq.y),
                           d * (a.z + bq.z), d * (a.w + bq.w));
    reinterpret_cast<float4*>(hs)[i4] = o;
}

// ---------- gather layer 1: x1[c] = b1 + di*( sum ew_i*h'[r_i] + h'[c] ) ----------
__global__ __launch_bounds__(256) void gather1_kernel(const ull* __restrict__ csr,
                                                      const int* __restrict__ rowptr,
                                                      const float* __restrict__ dinv,
                                                      const float* __restrict__ hs,
                                                      const float* __restrict__ b1,
                                                      float* __restrict__ x1, int N) {
    int t = blockIdx.x * 256 + threadIdx.x;
    int node = t >> 4, f = t & 15;
    if (node >= N) return;
    int s = rowptr[node], e = rowptr[node + 1];
    float di = dinv[node];
    float acc = hs[(size_t)node * NF1 + f];       // self-loop: h'[c]
    int i = s;
    for (; i + 1 < e; i += 2) {
        ull v0 = csr[i], v1 = csr[i + 1];
        int r0 = (int)(v0 & 0xffffffffull); float w0 = __uint_as_float((unsigned)(v0 >> 32));
        int r1 = (int)(v1 & 0xffffffffull); float w1 = __uint_as_float((unsigned)(v1 >> 32));
        acc += w0 * hs[(size_t)r0 * NF1 + f];
        acc += w1 * hs[(size_t)r1 * NF1 + f];
    }
    if (i < e) {
        ull v = csr[i];
        int r = (int)(v & 0xffffffffull); float w = __uint_as_float((unsigned)(v >> 32));
        acc += w * hs[(size_t)r * NF1 + f];
    }
    x1[(size_t)node * NF1 + f] = b1[f] + di * acc;
}

// ---------- GEMM2: hh' = dinv[j] * (relu(x1[j]) @ W2) ----------
__global__ __launch_bounds__(256) void gemm2_kernel(const float* __restrict__ x1,
                                                    const float* __restrict__ W2,
                                                    const float* __restrict__ dinv,
                                                    float* __restrict__ hh, int N) {
    int j = blockIdx.x * 256 + threadIdx.x;
    if (j >= N) return;
    float xr[NF1];
#pragma unroll
    for (int f = 0; f < NF1; f++) xr[f] = fmaxf(x1[(size_t)j * NF1 + f], 0.0f);
    float d = dinv[j];
#pragma unroll
    for (int c = 0; c < NF2; c++) {
        float acc = 0.0f;
#pragma unroll
        for (int f = 0; f < NF1; f++) acc += xr[f] * W2[f * NF2 + c];
        hh[(size_t)j * NF2 + c] = d * acc;
    }
}

// ---------- gather layer 2 + fused log-softmax ----------
__global__ __launch_bounds__(256) void gather2_lsm_kernel(const ull* __restrict__ csr,
                                                          const int* __restrict__ rowptr,
                                                          const float* __restrict__ dinv,
                                                          const float* __restrict__ hh,
                                                          const float* __restrict__ b2,
                                                          float* __restrict__ out, int N) {
    int t = blockIdx.x * 256 + threadIdx.x;
    int node = t >> 4, f = t & 15;
    bool act = (node < N) && (f < NF2);
    float acc = 0.0f;
    if (node < N) {
        int s = rowptr[node], e = rowptr[node + 1];
        float di = dinv[node];
        acc = act ? hh[(size_t)node * NF2 + f] : 0.0f;   // self-loop: hh'[c]
        int i = s;
        for (; i + 1 < e; i += 2) {
            ull v0 = csr[i], v1 = csr[i + 1];
            int r0 = (int)(v0 & 0xffffffffull); float w0 = __uint_as_float((unsigned)(v0 >> 32));
            int r1 = (int)(v1 & 0xffffffffull); float w1 = __uint_as_float((unsigned)(v1 >> 32));
            float h0 = (f < NF2) ? hh[(size_t)r0 * NF2 + f] : 0.0f;
            float h1 = (f < NF2) ? hh[(size_t)r1 * NF2 + f] : 0.0f;
            acc += w0 * h0 + w1 * h1;
        }
        if (i < e) {
            ull v = csr[i];
            int r = (int)(v & 0xffffffffull); float w = __uint_as_float((unsigned)(v >> 32));
            float hv = (f < NF2) ? hh[(size_t)r * NF2 + f] : 0.0f;
            acc += w * hv;
        }
        acc = b2[f] + di * acc;
    }
    // log-softmax across the 16-lane group (10 active lanes)
    float m = act ? acc : -INFINITY;
#pragma unroll
    for (int off = 1; off < 16; off <<= 1) m = fmaxf(m, __shfl_xor(m, off, 16));
    float p = act ? expf(acc - m) : 0.0f;
    float ssum = p;
#pragma unroll
    for (int off = 1; off < 16; off <<= 1) ssum += __shfl_xor(ssum, off, 16);
    if (act) out[(size_t)node * NF2 + f] = acc - m - logf(ssum);
}

extern "C" void kernel_launch(void* const* d_in, const int* in_sizes, int n_in,
                              void* d_out, int out_size, void* d_ws, size_t ws_size,
                              hipStream_t stream) {
    const float* x  = (const float*)d_in[0];
    const int*   ei = (const int*)d_in[1];
    const float* ew = (const float*)d_in[2];
    const float* W1 = (const float*)d_in[3];
    const float* b1 = (const float*)d_in[4];
    const float* W2 = (const float*)d_in[5];
    const float* b2 = (const float*)d_in[6];

    const int E = in_sizes[2];           // 3,200,000
    const int N = in_sizes[0] / FIN;     // 100,000
    const int* row = ei;
    const int* col = ei + E;

    const int NB   = (N + 511) >> 9;     // coarse buckets (196)
    const int NBLK = (E + EPB - 1) / EPB;

    float* out    = (float*)d_out;
    float* logits = out;                        // [N,10]
    float* x1     = out + (size_t)N * NF2;      // [N,16]

    char* ws = (char*)d_ws;
    size_t off = 0;
    auto alloc = [&](size_t bytes) { void* p = ws + off; off += (bytes + 255) / 256 * 256; return p; };
    ull*   pool    = (ull*)  alloc((size_t)E * 8);
    ull*   csr     = (ull*)  alloc((size_t)E * 8);
    float* part    = (float*)alloc((size_t)2 * N * NF1 * 4);   // split-K partials
    float* hs      = (float*)alloc((size_t)N * NF1 * 4);       // h' = dinv*(p0+p1)
    float* hh      = (float*)alloc((size_t)N * NF2 * 4 + 64);  // hh' = dinv*relu(x1)@W2
    float* dinv    = (float*)alloc((size_t)N * 4);
    int*   rowptr  = (int*)  alloc((size_t)(N + 1) * 4);
    int*   blkhist = (int*)  alloc((size_t)NB * NBLK * 4);
    int*   btot    = (int*)  alloc((size_t)NB * 4);
    int*   bbase   = (int*)  alloc((size_t)(NB + 1) * 4);
    (void)ws_size; (void)n_in; (void)out_size;

    dim3 blk(256);
    int gN    = (N + 255) / 256;
    int g16   = (N + 15) / 16;
    int nbRow = (N + 255) / 256;         // gemm1 row-blocks per K-half

    // build CSR (no global atomics)
    coarse_count_kernel<<<NBLK, blk, 0, stream>>>(col, blkhist, E, NB, NBLK);
    bucket_scan_kernel<<<NB, dim3(512), 0, stream>>>(blkhist, btot, NBLK);
    base_scan_kernel<<<1, blk, 0, stream>>>(btot, bbase, rowptr, NB, E, N);
    coarse_scatter_kernel<<<NBLK, blk, 0, stream>>>(row, col, ew, blkhist, bbase, pool, E, NB, NBLK);
    fine_sort_kernel<<<NB, dim3(1024), 0, stream>>>(pool, bbase, csr, rowptr, dinv, N);

    // layer 1
    gemm1_kernel<<<2 * nbRow, blk, 0, stream>>>(x, W1, part, N, nbRow);
    combine_scale_kernel<<<(N * NF1 / 4 + 255) / 256, blk, 0, stream>>>(part, dinv, hs, N);
    gather1_kernel<<<g16, blk, 0, stream>>>(csr, rowptr, dinv, hs, b1, x1, N);

    // layer 2
    gemm2_kernel<<<gN, blk, 0, stream>>>(x1, W2, dinv, hh, N);
    gather2_lsm_kernel<<<g16, blk, 0, stream>>>(csr, rowptr, dinv, hh, b2, logits, N);
}